// Round 5
// baseline (223.510 us; speedup 1.0000x reference)
//
#include <hip/hip_runtime.h>
#include <hip/hip_bf16.h>

typedef __attribute__((ext_vector_type(8))) short bf16x8;
typedef __attribute__((ext_vector_type(16))) float f32x16;
typedef __attribute__((ext_vector_type(4))) unsigned short ushort4v;

static __device__ __forceinline__ unsigned short f2bf(float f) {
  unsigned u = __float_as_uint(f);
  return (unsigned short)((u + 0x7FFFu + ((u >> 16) & 1u)) >> 16);
}
static __device__ __forceinline__ float silu_f(float v) { return v / (1.f + __expf(-v)); }

// ---- K0: fused weight pack (A-fragment order) + 4x4 avg pool ----
// A-frag pack: lane l holds row rb*32+(l&31), k = ks*16 + (l>>5)*8 + i.
// packed[((rb*NKS+ks)*64 + l)*8 + i]
__global__ void prep_k(const float* __restrict__ shw, const float* __restrict__ ew1,
                       const float* __restrict__ ew2, const float* __restrict__ x,
                       unsigned short* __restrict__ wshp, unsigned short* __restrict__ w1p,
                       unsigned short* __restrict__ w2p, float* __restrict__ xp) {
  const int bid = blockIdx.x;
  if (bid < 4352) {
    int idx = bid * 256 + threadIdx.x;
    if (idx < 65536) {  // shared_w [256,256], NKS=16
      int j = idx;
      int i = j & 7, l = (j >> 3) & 63, ks = (j >> 9) & 15, rb = j >> 13;
      int row = rb * 32 + (l & 31), k = ks * 16 + (l >> 5) * 8 + i;
      wshp[j] = f2bf(shw[row * 256 + k]);
    } else if (idx < 589824) {  // expert_w1 [4,512,256], NKS=16
      int j = idx - 65536;
      int i = j & 7, l = (j >> 3) & 63, ks = (j >> 9) & 15, rb = (j >> 13) & 15, e = j >> 17;
      int row = rb * 32 + (l & 31), k = ks * 16 + (l >> 5) * 8 + i;
      w1p[j] = f2bf(ew1[((size_t)e * 512 + row) * 256 + k]);
    } else if (idx < 1114112) {  // expert_w2 [4,256,512], NKS=32
      int j = idx - 589824;
      int i = j & 7, l = (j >> 3) & 63, ks = (j >> 9) & 31, rb = (j >> 14) & 7, e = j >> 17;
      int row = rb * 32 + (l & 31), k = ks * 16 + (l >> 5) * 8 + i;
      w2p[j] = f2bf(ew2[((size_t)e * 256 + row) * 512 + k]);
    }
  } else {
    int idx = (bid - 4352) * 256 + threadIdx.x;
    if (idx >= 16 * 256 * 196) return;
    int pj = idx % 14, tmp = idx / 14, pi = tmp % 14, bc = tmp / 14;
    const float* src = x + (size_t)bc * 3136 + pi * 4 * 56 + pj * 4;
    float s = 0.f;
#pragma unroll
    for (int u = 0; u < 4; ++u) {
      float4 v = *reinterpret_cast<const float4*>(src + u * 56);
      s += v.x + v.y + v.z + v.w;
    }
    xp[idx] = s * 0.0625f;
  }
}

// ---- K2: router 3x3 conv + SiLU + spatial sum. 128 blocks = 16 b x 8 rgroups(4 r).
// Weights via uniform global loads (SGPR), x-stencil cached in 9 regs across 4 r.
__global__ __launch_bounds__(256) void router_conv_k(const float* __restrict__ xp,
                                                     const float* __restrict__ rw1,
                                                     float* __restrict__ hsum) {
  const int b = blockIdx.x >> 3, rg = blockIdx.x & 7;
  __shared__ float xl[32][256];  // 32 channels, padded 16x16 planes
  __shared__ float red[4][4];
  const int t = threadIdx.x;
  const int pi = t / 14, pj = t % 14;
  float acc[4] = {0.f, 0.f, 0.f, 0.f};
  for (int i = t; i < 32 * 256; i += 256) (&xl[0][0])[i] = 0.f;  // borders stay zero
  for (int cc = 0; cc < 8; ++cc) {
    __syncthreads();
    for (int i = t; i < 32 * 196; i += 256) {
      int c = i / 196, px = i % 196;
      xl[c][(px / 14 + 1) * 16 + (px % 14 + 1)] =
          xp[((size_t)b * 256 + cc * 32 + c) * 196 + px];
    }
    __syncthreads();
    if (t < 196) {
#pragma unroll 4
      for (int c = 0; c < 32; ++c) {
        const float* xc = &xl[cc * 32 + c - cc * 32][pi * 16 + pj];  // xl[c][...]
        const float x0 = xc[0], x1 = xc[1], x2 = xc[2];
        const float x3 = xc[16], x4 = xc[17], x5 = xc[18];
        const float x6 = xc[32], x7 = xc[33], x8 = xc[34];
        // uniform index -> scalar loads (SGPR operands)
        const float* wg = rw1 + ((size_t)(rg * 4) * 256 + (cc * 32 + c)) * 9;
#pragma unroll
        for (int ri = 0; ri < 4; ++ri) {
          const float* wp = wg + (size_t)ri * 2304;
          acc[ri] += x0 * wp[0] + x1 * wp[1] + x2 * wp[2] + x3 * wp[3] + x4 * wp[4] +
                     x5 * wp[5] + x6 * wp[6] + x7 * wp[7] + x8 * wp[8];
        }
      }
    }
  }
#pragma unroll
  for (int ri = 0; ri < 4; ++ri) {
    float s = (t < 196) ? silu_f(acc[ri]) : 0.f;
#pragma unroll
    for (int off = 32; off > 0; off >>= 1) s += __shfl_down(s, off);
    if ((t & 63) == 0) red[t >> 6][ri] = s;
  }
  __syncthreads();
  if (t < 4) hsum[b * 32 + rg * 4 + t] = red[0][t] + red[1][t] + red[2][t] + red[3][t];
}

// ---- K3: logits -> softmax -> top-2 -> normalized weights ----
__global__ void topk_k(const float* __restrict__ hsum, const float* __restrict__ rw2,
                       float* __restrict__ selv, int* __restrict__ sele) {
  const int t = threadIdx.x;
  const int b = t >> 2, e = t & 3;
  float l = 0.f;
#pragma unroll
  for (int r = 0; r < 32; ++r) l += rw2[e * 32 + r] * hsum[b * 32 + r];
  l *= (1.f / 196.f);
  float m = fmaxf(l, __shfl_xor(l, 1));
  m = fmaxf(m, __shfl_xor(m, 2));
  float p = __expf(l - m);
  float sm = p + __shfl_xor(p, 1);
  sm += __shfl_xor(sm, 2);
  float prob = p / sm;
  float p0 = __shfl(prob, (b << 2) | 0);
  float p1 = __shfl(prob, (b << 2) | 1);
  float p2 = __shfl(prob, (b << 2) | 2);
  float p3 = __shfl(prob, (b << 2) | 3);
  if (e == 0) {
    float pr[4] = {p0, p1, p2, p3};
    int i1 = 0;
    for (int i = 1; i < 4; ++i)
      if (pr[i] > pr[i1]) i1 = i;
    int i2 = (i1 == 0) ? 1 : 0;
    for (int i = 0; i < 4; ++i) {
      if (i == i1 || i == i2) continue;
      if (pr[i] > pr[i2]) i2 = i;
    }
    float denom = pr[i1] + pr[i2] + 1e-6f;
    selv[b * 2 + 0] = pr[i1] / denom;
    selv[b * 2 + 1] = pr[i2] / denom;
    sele[b * 2 + 0] = i1;
    sele[b * 2 + 1] = i2;
  }
}

// K=256 GEMM: 2x2 frags, depth-4 ring, sched_barrier fences so the compiler
// cannot sink the prefetch loads into the MFMA cluster (keeps 3 K-steps in flight).
static __device__ __forceinline__ void gemm_k256_p4(
    const unsigned short* __restrict__ A0, const unsigned short* __restrict__ A1,
    const unsigned short* B0, const unsigned short* B1, f32x16 acc[2][2]) {
  bf16x8 a0[4], a1[4], b0[4], b1[4];
#pragma unroll
  for (int s = 0; s < 3; ++s) {
    a0[s] = *reinterpret_cast<const bf16x8*>(A0 + s * 512);
    a1[s] = *reinterpret_cast<const bf16x8*>(A1 + s * 512);
    b0[s] = *reinterpret_cast<const bf16x8*>(B0 + s * 1024);
    b1[s] = *reinterpret_cast<const bf16x8*>(B1 + s * 1024);
  }
  __builtin_amdgcn_sched_barrier(0);
#pragma unroll
  for (int ks = 0; ks < 16; ++ks) {
    const int s = ks & 3;
    const int n = (ks + 3) & 3;
    if (ks < 13) {
      a0[n] = *reinterpret_cast<const bf16x8*>(A0 + (ks + 3) * 512);
      a1[n] = *reinterpret_cast<const bf16x8*>(A1 + (ks + 3) * 512);
      b0[n] = *reinterpret_cast<const bf16x8*>(B0 + (ks + 3) * 1024);
      b1[n] = *reinterpret_cast<const bf16x8*>(B1 + (ks + 3) * 1024);
    }
    __builtin_amdgcn_sched_barrier(0);
    __builtin_amdgcn_s_setprio(1);
    acc[0][0] = __builtin_amdgcn_mfma_f32_32x32x16_bf16(a0[s], b0[s], acc[0][0], 0, 0, 0);
    acc[0][1] = __builtin_amdgcn_mfma_f32_32x32x16_bf16(a0[s], b1[s], acc[0][1], 0, 0, 0);
    acc[1][0] = __builtin_amdgcn_mfma_f32_32x32x16_bf16(a1[s], b0[s], acc[1][0], 0, 0, 0);
    acc[1][1] = __builtin_amdgcn_mfma_f32_32x32x16_bf16(a1[s], b1[s], acc[1][1], 0, 0, 0);
    __builtin_amdgcn_s_setprio(0);
    __builtin_amdgcn_sched_barrier(0);
  }
}

// ---- K4: fused MoE main. 4 waves x 64px, rf=2 cf=2, frag-linear LDS ----
// xs/hs layout: [kgroup 0..31][px 0..63][8 ushorts] -- B-frags contiguous.
__global__ __launch_bounds__(256, 2) void moe_main_k(
    const float* __restrict__ x, const unsigned short* __restrict__ wshp,
    const unsigned short* __restrict__ w1p, const unsigned short* __restrict__ w2p,
    const float* __restrict__ selv, const int* __restrict__ sele,
    float* __restrict__ out) {
  constexpr int HW = 3136;
  __shared__ __align__(16) unsigned short xs[32 * 64 * 8];  // 32 KB
  __shared__ __align__(16) unsigned short hs[32 * 64 * 8];  // 32 KB

  const int b = blockIdx.x / 49, tile = blockIdx.x - b * 49;
  const int px0 = tile * 64;
  const int t = threadIdx.x;
  const int w = t >> 6, l = t & 63;
  const int l31 = l & 31, lh = l >> 5;

  // ---- stage x tile: thread handles px=l, channels w*64+cg*8+i ----
  {
    const float* xb = x + (size_t)b * 256 * HW + px0 + l;
#pragma unroll
    for (int cg = 0; cg < 8; ++cg) {
      const int c0 = w * 64 + cg * 8;
      alignas(16) unsigned short tmp[8];
#pragma unroll
      for (int i = 0; i < 8; ++i) tmp[i] = f2bf(xb[(size_t)(c0 + i) * HW]);
      *reinterpret_cast<bf16x8*>(&xs[((c0 >> 3) * 64 + l) * 8]) =
          *reinterpret_cast<const bf16x8*>(tmp);
    }
  }

  // per-lane B-frag base pointers (k element = (l>>5)*8 + i)
  const unsigned short* xB0 = xs + (lh * 64 + l31) * 8;
  const unsigned short* xB1 = xB0 + 32 * 8;
  const unsigned short* hB0 = hs + (lh * 64 + l31) * 8;
  const unsigned short* hB1 = hB0 + 32 * 8;

  f32x16 oacc[2][2];
#pragma unroll
  for (int i = 0; i < 2; ++i)
#pragma unroll
    for (int j = 0; j < 2; ++j)
#pragma unroll
      for (int r = 0; r < 16; ++r) oacc[i][j][r] = 0.f;

  __syncthreads();

  // ---- shared expert: out rows w*64..+64 (rb = w*2, w*2+1), K=256 ----
  {
    const unsigned short* A0 = wshp + (size_t)(w * 2) * 16 * 512 + l * 8;
    gemm_k256_p4(A0, A0 + 8192, xB0, xB1, oacc);
  }
#pragma unroll
  for (int i = 0; i < 2; ++i)
#pragma unroll
    for (int j = 0; j < 2; ++j)
#pragma unroll
      for (int r = 0; r < 16; ++r) oacc[i][j][r] = silu_f(oacc[i][j][r]);

  // ---- top-2 experts: hidden 512 rows in 2 phases of 256 ----
#pragma unroll 1
  for (int ei = 0; ei < 2; ++ei) {
    const int e = sele[b * 2 + ei];
    const float v = selv[b * 2 + ei];
#pragma unroll 1
    for (int ph = 0; ph < 2; ++ph) {
      f32x16 hacc[2][2];
#pragma unroll
      for (int i = 0; i < 2; ++i)
#pragma unroll
        for (int j = 0; j < 2; ++j)
#pragma unroll
          for (int r = 0; r < 16; ++r) hacc[i][j][r] = 0.f;
      // stage1: hid rows ph*256 + w*64 ..+64 (rb = ph*8 + w*2 + rfi), K=256
      {
        const unsigned short* A0 =
            w1p + (size_t)(e * 16 + ph * 8 + w * 2) * 16 * 512 + l * 8;
        gemm_k256_p4(A0, A0 + 8192, xB0, xB1, hacc);
      }
      __syncthreads();  // previous stage2 readers of hs are done
      // v*silu(hid) -> bf16 -> hs (frag-linear 8B writes)
#pragma unroll
      for (int rfi = 0; rfi < 2; ++rfi)
#pragma unroll
        for (int cf = 0; cf < 2; ++cf) {
#pragma unroll
          for (int g = 0; g < 4; ++g) {
            alignas(8) unsigned short pk[4];
#pragma unroll
            for (int j = 0; j < 4; ++j)
              pk[j] = f2bf(v * silu_f(hacc[rfi][cf][g * 4 + j]));
            // phase-local row = w*64 + rfi*32 + g*8 + lh*4 + j
            const int kg = w * 8 + rfi * 4 + g;
            const int ui = (kg * 64 + cf * 32 + l31) * 8 + lh * 4;
            *reinterpret_cast<ushort4v*>(&hs[ui]) = *reinterpret_cast<const ushort4v*>(pk);
          }
        }
      __syncthreads();
      // stage2: out rows w*64..+64 (rb = w*2 + rfi), K = this phase's 256
      {
        const unsigned short* A0 =
            w2p + ((size_t)(e * 8 + w * 2) * 32 + ph * 16) * 512 + l * 8;
        gemm_k256_p4(A0, A0 + 16384, hB0, hB1, oacc);
      }
    }
  }

  // ---- write out[b, o, px] ----
#pragma unroll
  for (int rfi = 0; rfi < 2; ++rfi)
#pragma unroll
    for (int cf = 0; cf < 2; ++cf)
#pragma unroll
      for (int r = 0; r < 16; ++r) {
        const int o = w * 64 + rfi * 32 + (r & 3) + 8 * (r >> 2) + 4 * lh;
        out[((size_t)b * 256 + o) * HW + px0 + cf * 32 + l31] = oacc[rfi][cf][r];
      }
}

extern "C" void kernel_launch(void* const* d_in, const int* in_sizes, int n_in,
                              void* d_out, int out_size, void* d_ws, size_t ws_size,
                              hipStream_t stream) {
  const float* x = (const float*)d_in[0];
  const float* rw1 = (const float*)d_in[1];
  const float* rw2 = (const float*)d_in[2];
  const float* ew1 = (const float*)d_in[3];
  const float* ew2 = (const float*)d_in[4];
  const float* shw = (const float*)d_in[5];
  float* out = (float*)d_out;
  char* ws = (char*)d_ws;

  float* xp = (float*)(ws);                                // 3,211,264 B
  float* hsum = (float*)(ws + 3211264);
  float* selv = (float*)(ws + 3213312);
  int* sele = (int*)(ws + 3213440);
  unsigned short* wshp = (unsigned short*)(ws + 3213568);  // 128 KB
  unsigned short* w1p = wshp + 65536;                      // 1 MB
  unsigned short* w2p = w1p + 524288;                      // 1 MB

  prep_k<<<7488, 256, 0, stream>>>(shw, ew1, ew2, x, wshp, w1p, w2p, xp);
  router_conv_k<<<128, 256, 0, stream>>>(xp, rw1, hsum);
  topk_k<<<1, 64, 0, stream>>>(hsum, rw2, selv, sele);
  moe_main_k<<<784, 256, 0, stream>>>(x, wshp, w1p, w2p, selv, sele, out);
}

// Round 6
// 181.341 us; speedup vs baseline: 1.2325x; 1.2325x over previous
//
#include <hip/hip_runtime.h>
#include <hip/hip_bf16.h>

typedef __attribute__((ext_vector_type(8))) short bf16x8;
typedef __attribute__((ext_vector_type(16))) float f32x16;
typedef __attribute__((ext_vector_type(4))) unsigned short ushort4v;

static __device__ __forceinline__ unsigned short f2bf(float f) {
  unsigned u = __float_as_uint(f);
  return (unsigned short)((u + 0x7FFFu + ((u >> 16) & 1u)) >> 16);
}
static __device__ __forceinline__ float silu_f(float v) { return v / (1.f + __expf(-v)); }

// ---- K0: fused weight pack (A-fragment order) + 4x4 avg pool ----
// A-frag pack: lane l holds row rb*32+(l&31), k = ks*16 + (l>>5)*8 + i.
// packed[((rb*NKS+ks)*64 + l)*8 + i]
__global__ void prep_k(const float* __restrict__ shw, const float* __restrict__ ew1,
                       const float* __restrict__ ew2, const float* __restrict__ x,
                       unsigned short* __restrict__ wshp, unsigned short* __restrict__ w1p,
                       unsigned short* __restrict__ w2p, float* __restrict__ xp) {
  const int bid = blockIdx.x;
  if (bid < 4352) {
    int idx = bid * 256 + threadIdx.x;
    if (idx < 65536) {  // shared_w [256,256], NKS=16
      int j = idx;
      int i = j & 7, l = (j >> 3) & 63, ks = (j >> 9) & 15, rb = j >> 13;
      int row = rb * 32 + (l & 31), k = ks * 16 + (l >> 5) * 8 + i;
      wshp[j] = f2bf(shw[row * 256 + k]);
    } else if (idx < 589824) {  // expert_w1 [4,512,256], NKS=16
      int j = idx - 65536;
      int i = j & 7, l = (j >> 3) & 63, ks = (j >> 9) & 15, rb = (j >> 13) & 15, e = j >> 17;
      int row = rb * 32 + (l & 31), k = ks * 16 + (l >> 5) * 8 + i;
      w1p[j] = f2bf(ew1[((size_t)e * 512 + row) * 256 + k]);
    } else if (idx < 1114112) {  // expert_w2 [4,256,512], NKS=32
      int j = idx - 589824;
      int i = j & 7, l = (j >> 3) & 63, ks = (j >> 9) & 31, rb = (j >> 14) & 7, e = j >> 17;
      int row = rb * 32 + (l & 31), k = ks * 16 + (l >> 5) * 8 + i;
      w2p[j] = f2bf(ew2[((size_t)e * 256 + row) * 512 + k]);
    }
  } else {
    int idx = (bid - 4352) * 256 + threadIdx.x;
    if (idx >= 16 * 256 * 196) return;
    int pj = idx % 14, tmp = idx / 14, pi = tmp % 14, bc = tmp / 14;
    const float* src = x + (size_t)bc * 3136 + pi * 4 * 56 + pj * 4;
    float s = 0.f;
#pragma unroll
    for (int u = 0; u < 4; ++u) {
      float4 v = *reinterpret_cast<const float4*>(src + u * 56);
      s += v.x + v.y + v.z + v.w;
    }
    xp[idx] = s * 0.0625f;
  }
}

// ---- K2: router 3x3 conv (pad 1) + SiLU + spatial sum -> hsum[16,32] ----
// (reverted to the proven 512-block LDS version)
__global__ __launch_bounds__(256) void router_conv_k(const float* __restrict__ xp,
                                                     const float* __restrict__ rw1,
                                                     float* __restrict__ hsum) {
  const int b = blockIdx.x >> 5, r = blockIdx.x & 31;
  __shared__ float wl[2304];
  __shared__ float xl[32][256];
  __shared__ float red[4];
  const int t = threadIdx.x;
  for (int i = t; i < 2304; i += 256) wl[i] = rw1[r * 2304 + i];
  for (int i = t; i < 32 * 256; i += 256) (&xl[0][0])[i] = 0.f;
  const int pi = t / 14, pj = t % 14;
  float acc = 0.f;
  for (int cc = 0; cc < 8; ++cc) {
    __syncthreads();
    for (int i = t; i < 32 * 196; i += 256) {
      int c = i / 196, px = i % 196;
      xl[c][(px / 14 + 1) * 16 + (px % 14 + 1)] =
          xp[((size_t)b * 256 + cc * 32 + c) * 196 + px];
    }
    __syncthreads();
    if (t < 196) {
      for (int c = 0; c < 32; ++c) {
        const float* wp = &wl[(cc * 32 + c) * 9];
        const float* xc = &xl[c][pi * 16 + pj];
#pragma unroll
        for (int u = 0; u < 3; ++u)
#pragma unroll
          for (int v = 0; v < 3; ++v) acc += xc[u * 16 + v] * wp[u * 3 + v];
      }
    }
  }
  float s = (t < 196) ? silu_f(acc) : 0.f;
#pragma unroll
  for (int off = 32; off > 0; off >>= 1) s += __shfl_down(s, off);
  if ((t & 63) == 0) red[t >> 6] = s;
  __syncthreads();
  if (t == 0) hsum[b * 32 + r] = red[0] + red[1] + red[2] + red[3];
}

// ---- K3: logits -> softmax -> top-2 -> normalized weights ----
__global__ void topk_k(const float* __restrict__ hsum, const float* __restrict__ rw2,
                       float* __restrict__ selv, int* __restrict__ sele) {
  const int t = threadIdx.x;
  const int b = t >> 2, e = t & 3;
  float l = 0.f;
#pragma unroll
  for (int r = 0; r < 32; ++r) l += rw2[e * 32 + r] * hsum[b * 32 + r];
  l *= (1.f / 196.f);
  float m = fmaxf(l, __shfl_xor(l, 1));
  m = fmaxf(m, __shfl_xor(m, 2));
  float p = __expf(l - m);
  float sm = p + __shfl_xor(p, 1);
  sm += __shfl_xor(sm, 2);
  float prob = p / sm;
  float p0 = __shfl(prob, (b << 2) | 0);
  float p1 = __shfl(prob, (b << 2) | 1);
  float p2 = __shfl(prob, (b << 2) | 2);
  float p3 = __shfl(prob, (b << 2) | 3);
  if (e == 0) {
    float pr[4] = {p0, p1, p2, p3};
    int i1 = 0;
    for (int i = 1; i < 4; ++i)
      if (pr[i] > pr[i1]) i1 = i;
    int i2 = (i1 == 0) ? 1 : 0;
    for (int i = 0; i < 4; ++i) {
      if (i == i1 || i == i2) continue;
      if (pr[i] > pr[i2]) i2 = i;
    }
    float denom = pr[i1] + pr[i2] + 1e-6f;
    selv[b * 2 + 0] = pr[i1] / denom;
    selv[b * 2 + 1] = pr[i2] / denom;
    sele[b * 2 + 0] = i1;
    sele[b * 2 + 1] = i2;
  }
}

// rf=2 GEMM: 2 row-blocks x 2 px-blocks, 2-deep pipeline. NKS k-steps.
// A advance 512 ushorts/ks (global packed); B advance 1024 ushorts/ks (LDS).
template <int NKS>
static __device__ __forceinline__ void gemm_rf2(
    const unsigned short* __restrict__ A0, const unsigned short* __restrict__ A1,
    const unsigned short* B0, const unsigned short* B1, f32x16 acc[2][2]) {
  bf16x8 aA[2], bA[2], aB[2], bB[2];
  aA[0] = *reinterpret_cast<const bf16x8*>(A0);
  aA[1] = *reinterpret_cast<const bf16x8*>(A1);
  bA[0] = *reinterpret_cast<const bf16x8*>(B0);
  bA[1] = *reinterpret_cast<const bf16x8*>(B1);
#pragma unroll
  for (int kk = 0; kk < NKS; kk += 2) {
    aB[0] = *reinterpret_cast<const bf16x8*>(A0 + (kk + 1) * 512);
    aB[1] = *reinterpret_cast<const bf16x8*>(A1 + (kk + 1) * 512);
    bB[0] = *reinterpret_cast<const bf16x8*>(B0 + (kk + 1) * 1024);
    bB[1] = *reinterpret_cast<const bf16x8*>(B1 + (kk + 1) * 1024);
    acc[0][0] = __builtin_amdgcn_mfma_f32_32x32x16_bf16(aA[0], bA[0], acc[0][0], 0, 0, 0);
    acc[0][1] = __builtin_amdgcn_mfma_f32_32x32x16_bf16(aA[0], bA[1], acc[0][1], 0, 0, 0);
    acc[1][0] = __builtin_amdgcn_mfma_f32_32x32x16_bf16(aA[1], bA[0], acc[1][0], 0, 0, 0);
    acc[1][1] = __builtin_amdgcn_mfma_f32_32x32x16_bf16(aA[1], bA[1], acc[1][1], 0, 0, 0);
    if (kk + 2 < NKS) {
      aA[0] = *reinterpret_cast<const bf16x8*>(A0 + (kk + 2) * 512);
      aA[1] = *reinterpret_cast<const bf16x8*>(A1 + (kk + 2) * 512);
      bA[0] = *reinterpret_cast<const bf16x8*>(B0 + (kk + 2) * 1024);
      bA[1] = *reinterpret_cast<const bf16x8*>(B1 + (kk + 2) * 1024);
    }
    acc[0][0] = __builtin_amdgcn_mfma_f32_32x32x16_bf16(aB[0], bB[0], acc[0][0], 0, 0, 0);
    acc[0][1] = __builtin_amdgcn_mfma_f32_32x32x16_bf16(aB[0], bB[1], acc[0][1], 0, 0, 0);
    acc[1][0] = __builtin_amdgcn_mfma_f32_32x32x16_bf16(aB[1], bB[0], acc[1][0], 0, 0, 0);
    acc[1][1] = __builtin_amdgcn_mfma_f32_32x32x16_bf16(aB[1], bB[1], acc[1][1], 0, 0, 0);
  }
}

// rf=1 GEMM (stage1 chunks): 1 row-block x 2 px-blocks, K=256 (16 ks).
static __device__ __forceinline__ void gemm_rf1_k256(
    const unsigned short* __restrict__ A0, const unsigned short* B0,
    const unsigned short* B1, f32x16 acc[2]) {
  bf16x8 aA, bA[2], aB, bB[2];
  aA = *reinterpret_cast<const bf16x8*>(A0);
  bA[0] = *reinterpret_cast<const bf16x8*>(B0);
  bA[1] = *reinterpret_cast<const bf16x8*>(B1);
#pragma unroll
  for (int kk = 0; kk < 16; kk += 2) {
    aB = *reinterpret_cast<const bf16x8*>(A0 + (kk + 1) * 512);
    bB[0] = *reinterpret_cast<const bf16x8*>(B0 + (kk + 1) * 1024);
    bB[1] = *reinterpret_cast<const bf16x8*>(B1 + (kk + 1) * 1024);
    acc[0] = __builtin_amdgcn_mfma_f32_32x32x16_bf16(aA, bA[0], acc[0], 0, 0, 0);
    acc[1] = __builtin_amdgcn_mfma_f32_32x32x16_bf16(aA, bA[1], acc[1], 0, 0, 0);
    if (kk + 2 < 16) {
      aA = *reinterpret_cast<const bf16x8*>(A0 + (kk + 2) * 512);
      bA[0] = *reinterpret_cast<const bf16x8*>(B0 + (kk + 2) * 1024);
      bA[1] = *reinterpret_cast<const bf16x8*>(B1 + (kk + 2) * 1024);
    }
    acc[0] = __builtin_amdgcn_mfma_f32_32x32x16_bf16(aB, bB[0], acc[0], 0, 0, 0);
    acc[1] = __builtin_amdgcn_mfma_f32_32x32x16_bf16(aB, bB[1], acc[1], 0, 0, 0);
  }
}

// ---- K4: fused MoE main. 4 waves x 64px, 48 KB LDS -> 3 blocks/CU ----
// xs: [kgroup 0..31][px 0..63][8] (32 KB).  hs: [kgroup 0..15][px][8] (16 KB),
// hidden processed in 4 chunks of 128 rows per expert.
__global__ __launch_bounds__(256, 3) void moe_main_k(
    const float* __restrict__ x, const unsigned short* __restrict__ wshp,
    const unsigned short* __restrict__ w1p, const unsigned short* __restrict__ w2p,
    const float* __restrict__ selv, const int* __restrict__ sele,
    float* __restrict__ out) {
  constexpr int HW = 3136;
  __shared__ __align__(16) unsigned short xs[32 * 64 * 8];  // 32 KB
  __shared__ __align__(16) unsigned short hs[16 * 64 * 8];  // 16 KB

  const int b = blockIdx.x / 49, tile = blockIdx.x - b * 49;
  const int px0 = tile * 64;
  const int t = threadIdx.x;
  const int w = t >> 6, l = t & 63;
  const int l31 = l & 31, lh = l >> 5;

  // ---- stage x tile: thread handles px=l, channels w*64+cg*8+i ----
  {
    const float* xb = x + (size_t)b * 256 * HW + px0 + l;
#pragma unroll
    for (int cg = 0; cg < 8; ++cg) {
      const int c0 = w * 64 + cg * 8;
      alignas(16) unsigned short tmp[8];
#pragma unroll
      for (int i = 0; i < 8; ++i) tmp[i] = f2bf(xb[(size_t)(c0 + i) * HW]);
      *reinterpret_cast<bf16x8*>(&xs[((c0 >> 3) * 64 + l) * 8]) =
          *reinterpret_cast<const bf16x8*>(tmp);
    }
  }

  // per-lane B-frag base pointers (k element = (l>>5)*8 + i)
  const unsigned short* xB0 = xs + (lh * 64 + l31) * 8;
  const unsigned short* xB1 = xB0 + 32 * 8;
  const unsigned short* hB0 = hs + (lh * 64 + l31) * 8;
  const unsigned short* hB1 = hB0 + 32 * 8;

  f32x16 oacc[2][2];
#pragma unroll
  for (int i = 0; i < 2; ++i)
#pragma unroll
    for (int j = 0; j < 2; ++j)
#pragma unroll
      for (int r = 0; r < 16; ++r) oacc[i][j][r] = 0.f;

  __syncthreads();

  // ---- shared expert: out rows w*64..+64 (rb = w*2, w*2+1), K=256 ----
  {
    const unsigned short* A0 = wshp + (size_t)(w * 2) * 16 * 512 + l * 8;
    gemm_rf2<16>(A0, A0 + 8192, xB0, xB1, oacc);
  }
#pragma unroll
  for (int i = 0; i < 2; ++i)
#pragma unroll
    for (int j = 0; j < 2; ++j)
#pragma unroll
      for (int r = 0; r < 16; ++r) oacc[i][j][r] = silu_f(oacc[i][j][r]);

  // ---- top-2 experts: hidden 512 rows in 4 chunks of 128 per expert ----
#pragma unroll 1
  for (int ei = 0; ei < 2; ++ei) {
    const int e = sele[b * 2 + ei];
    const float v = selv[b * 2 + ei];
#pragma unroll 1
    for (int ch = 0; ch < 4; ++ch) {
      // stage1: hid rows ch*128 + w*32 ..+32 (rb = e*16 + ch*4 + w), K=256
      f32x16 hacc[2];
#pragma unroll
      for (int cf = 0; cf < 2; ++cf)
#pragma unroll
        for (int r = 0; r < 16; ++r) hacc[cf][r] = 0.f;
      {
        const unsigned short* A0 =
            w1p + (size_t)(e * 16 + ch * 4 + w) * 16 * 512 + l * 8;
        gemm_rf1_k256(A0, xB0, xB1, hacc);
      }
      __syncthreads();  // previous stage2 readers of hs are done
      // v*silu(hid) -> bf16 -> hs (frag-linear 8B writes)
#pragma unroll
      for (int cf = 0; cf < 2; ++cf) {
#pragma unroll
        for (int g = 0; g < 4; ++g) {
          alignas(8) unsigned short pk[4];
#pragma unroll
          for (int j = 0; j < 4; ++j) pk[j] = f2bf(v * silu_f(hacc[cf][g * 4 + j]));
          // chunk-local row = w*32 + g*8 + lh*4 + j  -> kgroup = w*4 + g
          const int kg = w * 4 + g;
          const int ui = (kg * 64 + cf * 32 + l31) * 8 + lh * 4;
          *reinterpret_cast<ushort4v*>(&hs[ui]) = *reinterpret_cast<const ushort4v*>(pk);
        }
      }
      __syncthreads();
      // stage2: out rows w*64..+64 (rb = w*2 + rfi), K = this chunk's 128
      {
        const unsigned short* A0 =
            w2p + ((size_t)(e * 8 + w * 2) * 32 + ch * 8) * 512 + l * 8;
        gemm_rf2<8>(A0, A0 + 16384, hB0, hB1, oacc);
      }
    }
  }

  // ---- write out[b, o, px] ----
#pragma unroll
  for (int rfi = 0; rfi < 2; ++rfi)
#pragma unroll
    for (int cf = 0; cf < 2; ++cf)
#pragma unroll
      for (int r = 0; r < 16; ++r) {
        const int o = w * 64 + rfi * 32 + (r & 3) + 8 * (r >> 2) + 4 * lh;
        out[((size_t)b * 256 + o) * HW + px0 + cf * 32 + l31] = oacc[rfi][cf][r];
      }
}

extern "C" void kernel_launch(void* const* d_in, const int* in_sizes, int n_in,
                              void* d_out, int out_size, void* d_ws, size_t ws_size,
                              hipStream_t stream) {
  const float* x = (const float*)d_in[0];
  const float* rw1 = (const float*)d_in[1];
  const float* rw2 = (const float*)d_in[2];
  const float* ew1 = (const float*)d_in[3];
  const float* ew2 = (const float*)d_in[4];
  const float* shw = (const float*)d_in[5];
  float* out = (float*)d_out;
  char* ws = (char*)d_ws;

  float* xp = (float*)(ws);                                // 3,211,264 B
  float* hsum = (float*)(ws + 3211264);
  float* selv = (float*)(ws + 3213312);
  int* sele = (int*)(ws + 3213440);
  unsigned short* wshp = (unsigned short*)(ws + 3213568);  // 128 KB
  unsigned short* w1p = wshp + 65536;                      // 1 MB
  unsigned short* w2p = w1p + 524288;                      // 1 MB

  prep_k<<<7488, 256, 0, stream>>>(shw, ew1, ew2, x, wshp, w1p, w2p, xp);
  router_conv_k<<<512, 256, 0, stream>>>(xp, rw1, hsum);
  topk_k<<<1, 64, 0, stream>>>(hsum, rw2, selv, sele);
  moe_main_k<<<784, 256, 0, stream>>>(x, wshp, w1p, w2p, selv, sele, out);
}